// Round 1
// baseline (85.379 us; speedup 1.0000x reference)
//
#include <hip/hip_runtime.h>
#include <hip/hip_bf16.h>
#include <cstdint>

// Problem constants (from reference): L=12, B=8192, D=1024, K=64
#define NL 12
#define NB 8192
#define ND 1024
#define NK 64
#define TB 16   // b-rows per block

typedef __attribute__((ext_vector_type(8))) short bf16x8;
typedef __attribute__((ext_vector_type(4))) float f32x4;

__device__ __forceinline__ unsigned short f2bf(float f) {
  union { float f; unsigned int u; } v; v.f = f;
  unsigned int u = v.u;
  u += 0x7FFFu + ((u >> 16) & 1u);   // round-to-nearest-even
  return (unsigned short)(u >> 16);
}

__global__ void __launch_bounds__(256)
fused_mean_gemm_tanh(const float* __restrict__ x, const float* __restrict__ W,
                     const float* __restrict__ bias, float* __restrict__ out) {
  // LDS: xm tile, [TB][1024] bf16, row stride 2048 B, XOR-swizzled (T2)
  __shared__ __align__(16) unsigned char xs[TB * 2048];

  const int tid = threadIdx.x;
  const int b0 = blockIdx.x * TB;

  // ---------------- Phase 1: xm = sum_l x[l, b0+i, :]  (HBM-bound pass) ----
  // Row i handled at iteration i by the whole block: 256 threads x float4 = 4KB row.
  const float4* x4 = (const float4*)x;
  for (int i = 0; i < TB; ++i) {
    const float4* p = x4 + (size_t)(b0 + i) * (ND / 4) + tid;
    float4 a = p[0];
#pragma unroll
    for (int l = 1; l < NL; ++l) {
      float4 v = p[(size_t)l * (NB * (ND / 4))];
      a.x += v.x; a.y += v.y; a.z += v.z; a.w += v.w;
    }
    unsigned int lo = (unsigned)f2bf(a.x) | ((unsigned)f2bf(a.y) << 16);
    unsigned int hi = (unsigned)f2bf(a.z) | ((unsigned)f2bf(a.w) << 16);
    int byte = i * 2048 + tid * 8;
    byte ^= (i & 7) << 4;            // T2 XOR swizzle (row-based, bits 4-6)
    uint2 u; u.x = lo; u.y = hi;
    *(uint2*)(xs + byte) = u;
  }
  __syncthreads();

  // ---------------- Phase 2: out[b0+m][k] = tanh(dot/12 + bias) via MFMA ---
  const int lane = tid & 63;
  const int w    = tid >> 6;     // wave id 0..3 -> k-tile
  const int mn   = lane & 15;    // A: b-row | B: W-row (k) | D: col (k)
  const int g    = lane >> 4;    // k-group within fragment
  const int kn0  = w * 16;

  f32x4 acc = {0.f, 0.f, 0.f, 0.f};
  const float* Wrow = W + (size_t)(kn0 + mn) * ND;
  const int abase = mn * 2048 + 16 * g;
  const int axor  = (mn & 7) << 4;

#pragma unroll 4
  for (int step = 0; step < 32; ++step) {
    int byte = (abase + 64 * step) ^ axor;
    bf16x8 afrag = *(const bf16x8*)(xs + byte);     // ds_read_b128, swizzled

    const float* wp = Wrow + 32 * step + 8 * g;     // 8 consecutive fp32 of W row
    float4 w0 = *(const float4*)(wp);
    float4 w1 = *(const float4*)(wp + 4);
    bf16x8 bfrag;
    bfrag[0] = (short)f2bf(w0.x); bfrag[1] = (short)f2bf(w0.y);
    bfrag[2] = (short)f2bf(w0.z); bfrag[3] = (short)f2bf(w0.w);
    bfrag[4] = (short)f2bf(w1.x); bfrag[5] = (short)f2bf(w1.y);
    bfrag[6] = (short)f2bf(w1.z); bfrag[7] = (short)f2bf(w1.w);

    acc = __builtin_amdgcn_mfma_f32_16x16x32_bf16(afrag, bfrag, acc, 0, 0, 0);
  }

  // C/D layout (m89-verified): col = lane&15, row = 4*(lane>>4) + reg
  const float bv = bias[kn0 + mn];
#pragma unroll
  for (int r = 0; r < 4; ++r) {
    int row = 4 * g + r;
    float val = tanhf(acc[r] * (1.0f / 12.0f) + bv);
    out[(size_t)(b0 + row) * NK + kn0 + mn] = val;
  }
}

extern "C" void kernel_launch(void* const* d_in, const int* in_sizes, int n_in,
                              void* d_out, int out_size, void* d_ws, size_t ws_size,
                              hipStream_t stream) {
  const float* x    = (const float*)d_in[0];
  const float* W    = (const float*)d_in[1];
  const float* bias = (const float*)d_in[2];
  float* out = (float*)d_out;

  dim3 grid(NB / TB);   // 512 blocks
  dim3 block(256);
  hipLaunchKernelGGL(fused_mean_gemm_tanh, grid, block, 0, stream,
                     x, W, bias, out);
}

// Round 2
// 74.053 us; speedup vs baseline: 1.1529x; 1.1529x over previous
//
#include <hip/hip_runtime.h>
#include <hip/hip_bf16.h>
#include <cstdint>

// Problem constants (from reference): L=12, B=8192, D=1024, K=64
#define NL 12
#define NB 8192
#define ND 1024
#define NK 64
#define TB 16   // b-rows per block

typedef __attribute__((ext_vector_type(8))) short bf16x8;
typedef __attribute__((ext_vector_type(4))) float f32x4;

__device__ __forceinline__ unsigned short f2bf(float f) {
  union { float f; unsigned int u; } v; v.f = f;
  unsigned int u = v.u;
  u += 0x7FFFu + ((u >> 16) & 1u);   // round-to-nearest-even
  return (unsigned short)(u >> 16);
}

// ---------------------------------------------------------------- W -> bf16
__global__ void __launch_bounds__(256)
wconv_kernel(const float* __restrict__ W, uint2* __restrict__ Wb) {
  int i = blockIdx.x * 256 + threadIdx.x;          // 16384 float4s
  f32x4 v = *((const f32x4*)W + i);
  uint2 u;
  u.x = (unsigned)f2bf(v[0]) | ((unsigned)f2bf(v[1]) << 16);
  u.y = (unsigned)f2bf(v[2]) | ((unsigned)f2bf(v[3]) << 16);
  Wb[i] = u;
}

// ------------------------------------------------- fused mean+GEMM+tanh
__global__ void __launch_bounds__(512, 4)
fused_mean_gemm_tanh(const float* __restrict__ x,
                     const unsigned short* __restrict__ Wb,
                     const float* __restrict__ bias, float* __restrict__ out) {
  // xm tile: [TB][1024] bf16, row stride 2048 B, XOR-swizzled (T2)
  __shared__ __align__(16) unsigned char xs[TB * 2048];   // 32 KB
  __shared__ f32x4 pred[4 * 64];                          // 4 KB partials

  const int tid = threadIdx.x;
  const int b0 = blockIdx.x * TB;

  // -------- Phase 1: xm = sum_l x[l, b0+i, :]  (HBM-bound, NT loads) ------
  // 512 threads cover 2 rows per sweep; 8 sweeps.
  const int rhalf = tid >> 8;        // 0/1 -> which row of the pair
  const int t     = tid & 255;       // float4 index within the row
  const f32x4* x4 = (const f32x4*)x;

  for (int s = 0; s < 8; ++s) {
    const int i = 2 * s + rhalf;
    const f32x4* p = x4 + (size_t)(b0 + i) * (ND / 4) + t;
    f32x4 a = __builtin_nontemporal_load(p);
#pragma unroll
    for (int l = 1; l < NL; ++l) {
      f32x4 v = __builtin_nontemporal_load(p + (size_t)l * (NB * (ND / 4)));
      a += v;
    }
    unsigned int lo = (unsigned)f2bf(a[0]) | ((unsigned)f2bf(a[1]) << 16);
    unsigned int hi = (unsigned)f2bf(a[2]) | ((unsigned)f2bf(a[3]) << 16);
    int byte = i * 2048 + t * 8;
    byte ^= (i & 7) << 4;            // T2 XOR swizzle
    uint2 u; u.x = lo; u.y = hi;
    *(uint2*)(xs + byte) = u;
  }
  __syncthreads();

  // -------- Phase 2: out[b0+m][k] = tanh(dot/12 + bias) via MFMA ----------
  // 8 waves: wave w -> k-tile (w&3), K-half (w>>2). Pair (w, w+4) reduces.
  const int lane  = tid & 63;
  const int w     = tid >> 6;
  const int ktile = w & 3;
  const int khalf = w >> 2;
  const int mn    = lane & 15;       // A: b-row | B: W-row (k) | D: col (k)
  const int g     = lane >> 4;       // k-group within fragment
  const int kn0   = ktile * 16;

  f32x4 acc = {0.f, 0.f, 0.f, 0.f};
  const unsigned short* Wrow = Wb + (size_t)(kn0 + mn) * ND;
  const int abase = mn * 2048 + 16 * g;
  const int axor  = (mn & 7) << 4;

#pragma unroll 4
  for (int ss = 0; ss < 16; ++ss) {
    const int step = khalf * 16 + ss;
    int byte = (abase + 64 * step) ^ axor;
    bf16x8 afrag = *(const bf16x8*)(xs + byte);              // ds_read_b128
    bf16x8 bfrag = *(const bf16x8*)(Wrow + 32 * step + 8 * g); // 16B global
    acc = __builtin_amdgcn_mfma_f32_16x16x32_bf16(afrag, bfrag, acc, 0, 0, 0);
  }

  if (w >= 4) pred[(w - 4) * 64 + lane] = acc;
  __syncthreads();

  if (w < 4) {
    f32x4 o = pred[w * 64 + lane];
    acc += o;
    // C/D layout (m89-verified): col = lane&15, row = 4*(lane>>4) + reg
    const float bv = bias[kn0 + mn];
#pragma unroll
    for (int r = 0; r < 4; ++r) {
      int row = 4 * g + r;
      float val = tanhf(acc[r] * (1.0f / 12.0f) + bv);
      out[(size_t)(b0 + row) * NK + kn0 + mn] = val;
    }
  }
}

extern "C" void kernel_launch(void* const* d_in, const int* in_sizes, int n_in,
                              void* d_out, int out_size, void* d_ws, size_t ws_size,
                              hipStream_t stream) {
  const float* x    = (const float*)d_in[0];
  const float* W    = (const float*)d_in[1];
  const float* bias = (const float*)d_in[2];
  float* out = (float*)d_out;
  unsigned short* Wb = (unsigned short*)d_ws;   // 64*1024 bf16 = 128 KB

  hipLaunchKernelGGL(wconv_kernel, dim3(NK * ND / 4 / 256), dim3(256), 0,
                     stream, W, (uint2*)Wb);
  hipLaunchKernelGGL(fused_mean_gemm_tanh, dim3(NB / TB), dim3(512), 0, stream,
                     x, Wb, bias, out);
}